// Round 9
// baseline (359.103 us; speedup 1.0000x reference)
//
#include <hip/hip_runtime.h>
#include <hip/hip_bf16.h>

// VSSBlock: B=2 H=64 W=64 C=192 DM=384 N=16 R=12 K=4 L=4096
// R9: scan1 pairs direction k with its reverse k+2 (same pixels, reversed order):
//     u cached in regs, ONE atomicAdd per (pixel,d) for both chains (atomic 49->25MB).
//     Scans use 192-thread blocks (2048/1024 blocks) for balance. Combine writes h_in
//     to separate Hb (no in-place aliasing), 768x64. ysum zeroing fused into scan0;
//     LN+packw fused. 9 dispatches.

typedef __attribute__((ext_vector_type(8))) short short8;     // 8 bf16 = 4 VGPRs
typedef __attribute__((ext_vector_type(4))) float floatx4;    // fp32 accum frag

// ---------------- fused: LayerNorm (rows) + weight pack (tail blocks) ----------------
__global__ __launch_bounds__(256) void k_ln_packw(const float* __restrict__ in,
                                                  const float* __restrict__ g,
                                                  const float* __restrict__ be,
                                                  const float* __restrict__ ipw,
                                                  const float* __restrict__ xpw,
                                                  const float* __restrict__ opw,
                                                  __hip_bfloat16* __restrict__ xnb,
                                                  __hip_bfloat16* __restrict__ Wt1,
                                                  __hip_bfloat16* __restrict__ Wt2,
                                                  __hip_bfloat16* __restrict__ Wt3) {
  int bid = blockIdx.x;
  if (bid < 2048) {
    int row = bid * 4 + (threadIdx.x >> 6);
    int lane = threadIdx.x & 63;
    const float* x = in + (long)row * 192;
    float v0 = x[lane], v1 = x[lane + 64], v2 = x[lane + 128];
    float s = v0 + v1 + v2;
    float s2 = v0 * v0 + v1 * v1 + v2 * v2;
    #pragma unroll
    for (int o = 32; o > 0; o >>= 1) { s += __shfl_xor(s, o); s2 += __shfl_xor(s2, o); }
    float mu = s * (1.f / 192.f);
    float var = s2 * (1.f / 192.f) - mu * mu;
    float r = rsqrtf(var + 1e-6f);
    __hip_bfloat16* op = xnb + (long)row * 192;
    op[lane]       = __float2bfloat16((v0 - mu) * r * g[lane]       + be[lane]);
    op[lane + 64]  = __float2bfloat16((v1 - mu) * r * g[lane + 64]  + be[lane + 64]);
    op[lane + 128] = __float2bfloat16((v2 - mu) * r * g[lane + 128] + be[lane + 128]);
  } else {
    int idx = (bid - 2048) * 256 + threadIdx.x;
    if (idx < 147456) {                       // Wt1[n][k] = ipw[k][n]
      int n = idx / 192, k = idx - n * 192;
      Wt1[idx] = __float2bfloat16(ipw[(long)k * 768 + n]);
    } else if (idx < 147456 + 73728) {        // Wt2[j][d]
      int t = idx - 147456;
      int j = t / 384;
      float v = (j < 176) ? xpw[t] : 0.f;
      Wt2[t] = __float2bfloat16(v);
    } else if (idx < 147456 + 73728 + 73728) {// Wt3[n][k] = opw[k][n]
      int t = idx - 147456 - 73728;
      int n = t / 384, k = t - n * 384;
      Wt3[t] = __float2bfloat16(opw[(long)k * 192 + n]);
    }
  }
}

// direction map (involutions): pixel p <-> scan position l
__device__ __forceinline__ int inv_dir(int k, int p) {
  int pt = ((p & 63) << 6) | (p >> 6);
  if (k == 0) return p;
  if (k == 1) return pt;
  if (k == 2) return 4095 - p;
  return 4095 - pt;
}
__device__ __forceinline__ int dir_pix(int k, int l) { return inv_dir(k, l); }

// ---------------- bf16 MFMA GEMM: 64x64 tile, BK=64, XOR-swizzled LDS ----------------
// EPI 1: fp32 + Res; EPI 2: split bf16 -> CoB/Co2B [N=768]; EPI 3: scatter scan-order.
template <int EPI>
__global__ __launch_bounds__(256) void k_gemm_mfma(const __hip_bfloat16* __restrict__ A,
                                                   const __hip_bfloat16* __restrict__ Bt,
                                                   const float* __restrict__ Res,
                                                   float* __restrict__ Co,
                                                   __hip_bfloat16* __restrict__ CoB,
                                                   __hip_bfloat16* __restrict__ Co2B,
                                                   float* __restrict__ dtsS,
                                                   float* __restrict__ BsS,
                                                   float* __restrict__ CsS,
                                                   int M, int N, int Kk) {
  __shared__ __align__(16) short As[64 * 64];
  __shared__ __align__(16) short Bs[64 * 64];
  int tid = threadIdx.x;
  int wave = tid >> 6, lane = tid & 63;
  int mlane = lane & 15, quad = lane >> 4;
  int row0 = blockIdx.y * 64, col0 = blockIdx.x * 64;
  int wr = wave & 1, wc = wave >> 1;
  floatx4 acc[2][2];
  #pragma unroll
  for (int mi = 0; mi < 2; mi++)
    #pragma unroll
    for (int ni = 0; ni < 2; ni++) acc[mi][ni] = (floatx4){0.f, 0.f, 0.f, 0.f};

  for (int k0 = 0; k0 < Kk; k0 += 64) {
    #pragma unroll
    for (int c = tid; c < 512; c += 256) {
      int r = c >> 3, j = c & 7;
      *(float4*)&As[r * 64 + ((j ^ (r & 7)) << 3)] =
          *(const float4*)&A[(long)(row0 + r) * Kk + k0 + j * 8];
    }
    #pragma unroll
    for (int c = tid; c < 512; c += 256) {
      int r = c >> 3, j = c & 7;
      *(float4*)&Bs[r * 64 + ((j ^ (r & 7)) << 3)] =
          *(const float4*)&Bt[(long)(col0 + r) * Kk + k0 + j * 8];
    }
    __syncthreads();
    short8 af[2][2], bf[2][2];
    #pragma unroll
    for (int mi = 0; mi < 2; mi++) {
      int r = wr * 32 + mi * 16 + mlane;
      #pragma unroll
      for (int kk = 0; kk < 2; kk++) {
        int jx = (kk * 4 + quad) ^ (r & 7);
        af[mi][kk] = *(const short8*)&As[r * 64 + jx * 8];
      }
    }
    #pragma unroll
    for (int ni = 0; ni < 2; ni++) {
      int rn = wc * 32 + ni * 16 + mlane;
      #pragma unroll
      for (int kk = 0; kk < 2; kk++) {
        int jx = (kk * 4 + quad) ^ (rn & 7);
        bf[ni][kk] = *(const short8*)&Bs[rn * 64 + jx * 8];
      }
    }
    #pragma unroll
    for (int kk = 0; kk < 2; kk++)
      #pragma unroll
      for (int mi = 0; mi < 2; mi++)
        #pragma unroll
        for (int ni = 0; ni < 2; ni++)
          acc[mi][ni] = __builtin_amdgcn_mfma_f32_16x16x32_bf16(af[mi][kk], bf[ni][kk],
                                                                acc[mi][ni], 0, 0, 0);
    __syncthreads();
  }
  // C/D layout: col=lane&15, row=quad*4+reg  [m89-verified]
  #pragma unroll
  for (int mi = 0; mi < 2; mi++) {
    #pragma unroll
    for (int ni = 0; ni < 2; ni++) {
      int cc = col0 + wc * 32 + ni * 16 + mlane;
      #pragma unroll
      for (int i = 0; i < 4; i++) {
        int rr = row0 + wr * 32 + mi * 16 + quad * 4 + i;
        float v = acc[mi][ni][i];
        if (EPI == 1) {
          Co[(long)rr * N + cc] = v + Res[(long)rr * N + cc];
        } else if (EPI == 2) {
          if (cc < 384) CoB[(long)rr * 384 + cc] = __float2bfloat16(v);
          else          Co2B[(long)rr * 384 + (cc - 384)] = __float2bfloat16(v);
        } else {  // EPI == 3
          if (cc < 176) {
            int k4 = (cc >= 132) ? 3 : (cc >= 88) ? 2 : (cc >= 44) ? 1 : 0;
            int c = cc - k4 * 44;
            int b = rr >> 12, p = rr & 4095;
            int l = inv_dir(k4, p);
            long lbase = ((long)((b << 2) + k4) << 12) + l;
            if (c < 12)      dtsS[lbase * 12 + c] = v;
            else if (c < 28) BsS[lbase * 16 + (c - 12)] = v;
            else             CsS[lbase * 16 + (c - 28)] = v;
          }
        }
      }
    }
  }
}

// ---------------- depthwise 3x3 conv + bias + SiLU; bf16 in, bf16 out ----------------
__global__ __launch_bounds__(384) void k_conv(const __hip_bfloat16* __restrict__ xbufB,
                                              const float* __restrict__ cw,
                                              const float* __restrict__ cb,
                                              __hip_bfloat16* __restrict__ xcb) {
  int row = blockIdx.x;
  int b = row >> 12, p = row & 4095;
  int h = p >> 6, w0 = p & 63;
  int d = threadIdx.x;
  float acc = cb[d];
  const float* wt = cw + d * 9;
  #pragma unroll
  for (int dh = -1; dh <= 1; dh++) {
    int hh = h + dh;
    if (hh < 0 || hh > 63) continue;
    #pragma unroll
    for (int dw = -1; dw <= 1; dw++) {
      int ww = w0 + dw;
      if (ww < 0 || ww > 63) continue;
      acc += __bfloat162float(xbufB[((long)(b << 12) + (hh << 6) + ww) * 384 + d])
             * wt[(dh + 1) * 3 + (dw + 1)];
    }
  }
  float sg = 1.f / (1.f + __expf(-acc));
  xcb[(long)row * 384 + d] = __float2bfloat16(acc * sg);
}

// powers: pws[n] = r^(n+1), log-depth pairing
__device__ __forceinline__ void pow16(float r, float* pws) {
  pws[0] = r;
  #pragma unroll
  for (int n = 1; n < 16; n++) {
    int m = n + 1, c = (m + 1) / 2, f = m - c;
    pws[n] = pws[c - 1] * pws[f - 1];
  }
}

// ---------------- scan pass 0: 128 segs x 32 steps; 192-thread blocks (d half-split) ----
// Also zeroes its 1536-float slice of ysum (replaces the memset dispatch).
__global__ __launch_bounds__(192) void k_scan0(
    const float* __restrict__ dtsS, const float* __restrict__ BsS,
    const __hip_bfloat16* __restrict__ xcb,
    const float* __restrict__ A_logs, const float* __restrict__ dt_w,
    const float* __restrict__ dt_b,
    float* __restrict__ Eb, float* __restrict__ Dend,
    float* __restrict__ ysum) {
  int bid = blockIdx.x;               // ((bk*128 + s)*2 + half)
  {  // zero ysum slice: 2048 blocks x 1536 floats = 3,145,728
    float4 z4 = {0.f, 0.f, 0.f, 0.f};
    float4* zp = (float4*)(ysum + (long)bid * 1536) + threadIdx.x;
    zp[0] = z4; zp[192] = z4;
  }
  int half = bid & 1;
  int s = (bid >> 1) & 127, bk = bid >> 8;
  int k = bk & 3, b = bk >> 2;
  int d = half * 192 + threadIdx.x;
  float w[12];
  const float* dwp = dt_w + ((long)(k * 384) + d) * 12;
  #pragma unroll
  for (int r = 0; r < 12; r++) w[r] = dwp[r];
  float db = dt_b[k * 384 + d];
  const float* al = A_logs + ((long)(k * 384) + d) * 16;
  bool pw = true;
  float av[16];
  #pragma unroll
  for (int n = 0; n < 16; n++) {
    float a = __expf(al[n]);
    av[n] = -a;
    pw = pw && (fabsf(a - (float)(n + 1)) < 1e-3f);
  }
  float h[16];
  #pragma unroll
  for (int n = 0; n < 16; n++) h[n] = 0.f;
  float cum = 0.f;
  long lb = (long)bk * 4096 + s * 32;
  long bpix = (long)(b << 12);

  if (pw) {
    #pragma unroll 4
    for (int t = 0; t < 32; t++) {
      const float4* dq = (const float4*)(dtsS + (lb + t) * 12);
      float4 q0 = dq[0], q1 = dq[1], q2 = dq[2];
      float x = db + q0.x * w[0] + q0.y * w[1] + q0.z * w[2] + q0.w * w[3]
                   + q1.x * w[4] + q1.y * w[5] + q1.z * w[6] + q1.w * w[7]
                   + q2.x * w[8] + q2.y * w[9] + q2.z * w[10] + q2.w * w[11];
      float e = __expf(x);
      float delta = (x > 15.f) ? x : __logf(1.f + e);
      cum += delta;
      int p = dir_pix(k, s * 32 + t);
      float u = __bfloat162float(xcb[(bpix + p) * 384 + d]);
      float du = delta * u;
      float rr = __builtin_amdgcn_rcpf(1.f + e);  // exp(-softplus(x))
      float pws[16]; pow16(rr, pws);
      const float4* Bq = (const float4*)(BsS + (lb + t) * 16);
      float4 b0 = Bq[0], b1 = Bq[1], b2 = Bq[2], b3 = Bq[3];
      float Bl[16] = {b0.x, b0.y, b0.z, b0.w, b1.x, b1.y, b1.z, b1.w,
                      b2.x, b2.y, b2.z, b2.w, b3.x, b3.y, b3.z, b3.w};
      #pragma unroll
      for (int n = 0; n < 16; n++) h[n] = pws[n] * h[n] + du * Bl[n];
    }
  } else {
    for (int t = 0; t < 32; t++) {
      const float4* dq = (const float4*)(dtsS + (lb + t) * 12);
      float4 q0 = dq[0], q1 = dq[1], q2 = dq[2];
      float x = db + q0.x * w[0] + q0.y * w[1] + q0.z * w[2] + q0.w * w[3]
                   + q1.x * w[4] + q1.y * w[5] + q1.z * w[6] + q1.w * w[7]
                   + q2.x * w[8] + q2.y * w[9] + q2.z * w[10] + q2.w * w[11];
      float e = __expf(x);
      float delta = (x > 15.f) ? x : __logf(1.f + e);
      cum += delta;
      int p = dir_pix(k, s * 32 + t);
      float u = __bfloat162float(xcb[(bpix + p) * 384 + d]);
      float du = delta * u;
      const float4* Bq = (const float4*)(BsS + (lb + t) * 16);
      float4 b0 = Bq[0], b1 = Bq[1], b2 = Bq[2], b3 = Bq[3];
      float Bl[16] = {b0.x, b0.y, b0.z, b0.w, b1.x, b1.y, b1.z, b1.w,
                      b2.x, b2.y, b2.z, b2.w, b3.x, b3.y, b3.z, b3.w};
      #pragma unroll
      for (int n = 0; n < 16; n++) {
        float dA = __expf(delta * av[n]);
        h[n] = dA * h[n] + du * Bl[n];
      }
    }
  }
  long g = (long)bk * 128 + s;
  float* Ep = Eb + g * 6144 + d * 16;
  #pragma unroll
  for (int n = 0; n < 16; n++) Ep[n] = h[n];
  Dend[g * 384 + d] = cum;
}

// ---------------- combine: serial over 128 segs, h_in -> separate Hb (no aliasing) ----
__global__ __launch_bounds__(64) void k_combine(const float* __restrict__ Eb,
                                                const float* __restrict__ Dend,
                                                const float* __restrict__ A_logs,
                                                float* __restrict__ Hb) {
  int t = blockIdx.x * 64 + threadIdx.x;  // B*K*6144 = 49152
  int bk = t / 6144;
  int dn = t - bk * 6144;
  int k = bk & 3;
  int d = dn >> 4;
  float av = -__expf(A_logs[(long)k * 6144 + dn]);
  float h = 0.f;
  long ebase = (long)bk * 128 * 6144 + dn;
  long dbase = (long)bk * 128 * 384 + d;
  for (int s = 0; s < 128; s++) {
    Hb[ebase + (long)s * 6144] = h;
    h = __expf(av * Dend[dbase + (long)s * 384]) * h + Eb[ebase + (long)s * 6144];
  }
}

// ---------------- scan pass 1 (direction-paired): chains k and k+2 in one block ----
// 1024 blocks x 192 threads: bid = ((b*2+q)*128 + s)*2 + half; forward chain b*4+q,
// reverse chain b*4+q+2 (segment 127-s). Reverse pixel at step tt == forward pixel at
// 31-tt, so u is cached and ONE atomicAdd per (pixel,d) covers both chains.
__global__ __launch_bounds__(192) void k_scan1(
    const float* __restrict__ dtsS, const float* __restrict__ BsS,
    const float* __restrict__ CsS, const __hip_bfloat16* __restrict__ xcb,
    const float* __restrict__ A_logs, const float* __restrict__ dt_w,
    const float* __restrict__ dt_b, const float* __restrict__ Hb,
    float* __restrict__ ysum) {
  int bid = blockIdx.x;
  int half = bid & 1;
  int s = (bid >> 1) & 127;
  int q = (bid >> 8) & 1;
  int b = bid >> 9;
  int cf = b * 4 + q;        // forward chain
  int cr = cf + 2;           // reverse chain
  int sr = 127 - s;
  int d = half * 192 + threadIdx.x;

  float wf[12], wr2[12];
  const float* dwf = dt_w + ((long)(q * 384) + d) * 12;
  const float* dwr = dt_w + ((long)((q + 2) * 384) + d) * 12;
  #pragma unroll
  for (int r = 0; r < 12; r++) { wf[r] = dwf[r]; wr2[r] = dwr[r]; }
  float dbf = dt_b[q * 384 + d];
  float dbr = dt_b[(q + 2) * 384 + d];
  const float* alf = A_logs + ((long)(q * 384) + d) * 16;
  const float* alr = A_logs + ((long)((q + 2) * 384) + d) * 16;
  bool pw = true;
  float avf[16], avr[16];
  #pragma unroll
  for (int n = 0; n < 16; n++) {
    float a1 = __expf(alf[n]), a2 = __expf(alr[n]);
    avf[n] = -a1; avr[n] = -a2;
    pw = pw && (fabsf(a1 - (float)(n + 1)) < 1e-3f) && (fabsf(a2 - (float)(n + 1)) < 1e-3f);
  }
  long lbf = (long)cf * 4096 + s * 32;
  long lbr = (long)cr * 4096 + sr * 32;
  long bpix = (long)(b << 12);
  float h[16];
  float yreg[32], ureg[32];

  // ---- forward chain ----
  {
    const float* hp = Hb + ((long)cf * 128 + s) * 6144 + d * 16;
    #pragma unroll
    for (int n = 0; n < 16; n++) h[n] = hp[n];
  }
  if (pw) {
    #pragma unroll
    for (int t = 0; t < 32; t++) {
      const float4* dq = (const float4*)(dtsS + (lbf + t) * 12);
      float4 q0 = dq[0], q1 = dq[1], q2 = dq[2];
      float x = dbf + q0.x * wf[0] + q0.y * wf[1] + q0.z * wf[2] + q0.w * wf[3]
                    + q1.x * wf[4] + q1.y * wf[5] + q1.z * wf[6] + q1.w * wf[7]
                    + q2.x * wf[8] + q2.y * wf[9] + q2.z * wf[10] + q2.w * wf[11];
      float e = __expf(x);
      float delta = (x > 15.f) ? x : __logf(1.f + e);
      int p = dir_pix(q, s * 32 + t);
      float u = __bfloat162float(xcb[(bpix + p) * 384 + d]);
      ureg[t] = u;
      float du = delta * u;
      float rr = __builtin_amdgcn_rcpf(1.f + e);
      float pws[16]; pow16(rr, pws);
      const float4* Bq = (const float4*)(BsS + (lbf + t) * 16);
      float4 b0 = Bq[0], b1 = Bq[1], b2 = Bq[2], b3 = Bq[3];
      float Bl[16] = {b0.x, b0.y, b0.z, b0.w, b1.x, b1.y, b1.z, b1.w,
                      b2.x, b2.y, b2.z, b2.w, b3.x, b3.y, b3.z, b3.w};
      const float4* Cq = (const float4*)(CsS + (lbf + t) * 16);
      float4 c0 = Cq[0], c1 = Cq[1], c2 = Cq[2], c3 = Cq[3];
      float Cl[16] = {c0.x, c0.y, c0.z, c0.w, c1.x, c1.y, c1.z, c1.w,
                      c2.x, c2.y, c2.z, c2.w, c3.x, c3.y, c3.z, c3.w};
      float y = 0.f;
      #pragma unroll
      for (int n = 0; n < 16; n++) { h[n] = pws[n] * h[n] + du * Bl[n]; y += h[n] * Cl[n]; }
      yreg[t] = y;
    }
  } else {
    #pragma unroll
    for (int t = 0; t < 32; t++) {
      const float4* dq = (const float4*)(dtsS + (lbf + t) * 12);
      float4 q0 = dq[0], q1 = dq[1], q2 = dq[2];
      float x = dbf + q0.x * wf[0] + q0.y * wf[1] + q0.z * wf[2] + q0.w * wf[3]
                    + q1.x * wf[4] + q1.y * wf[5] + q1.z * wf[6] + q1.w * wf[7]
                    + q2.x * wf[8] + q2.y * wf[9] + q2.z * wf[10] + q2.w * wf[11];
      float e = __expf(x);
      float delta = (x > 15.f) ? x : __logf(1.f + e);
      int p = dir_pix(q, s * 32 + t);
      float u = __bfloat162float(xcb[(bpix + p) * 384 + d]);
      ureg[t] = u;
      float du = delta * u;
      const float4* Bq = (const float4*)(BsS + (lbf + t) * 16);
      float4 b0 = Bq[0], b1 = Bq[1], b2 = Bq[2], b3 = Bq[3];
      float Bl[16] = {b0.x, b0.y, b0.z, b0.w, b1.x, b1.y, b1.z, b1.w,
                      b2.x, b2.y, b2.z, b2.w, b3.x, b3.y, b3.z, b3.w};
      const float4* Cq = (const float4*)(CsS + (lbf + t) * 16);
      float4 c0 = Cq[0], c1 = Cq[1], c2 = Cq[2], c3 = Cq[3];
      float Cl[16] = {c0.x, c0.y, c0.z, c0.w, c1.x, c1.y, c1.z, c1.w,
                      c2.x, c2.y, c2.z, c2.w, c3.x, c3.y, c3.z, c3.w};
      float y = 0.f;
      #pragma unroll
      for (int n = 0; n < 16; n++) {
        float dA = __expf(delta * avf[n]);
        h[n] = dA * h[n] + du * Bl[n];
        y += h[n] * Cl[n];
      }
      yreg[t] = y;
    }
  }
  // ---- reverse chain (same pixels, reversed): step tt -> forward slot 31-tt ----
  {
    const float* hp = Hb + ((long)cr * 128 + sr) * 6144 + d * 16;
    #pragma unroll
    for (int n = 0; n < 16; n++) h[n] = hp[n];
  }
  if (pw) {
    #pragma unroll
    for (int tt = 0; tt < 32; tt++) {
      const float4* dq = (const float4*)(dtsS + (lbr + tt) * 12);
      float4 q0 = dq[0], q1 = dq[1], q2 = dq[2];
      float x = dbr + q0.x * wr2[0] + q0.y * wr2[1] + q0.z * wr2[2] + q0.w * wr2[3]
                    + q1.x * wr2[4] + q1.y * wr2[5] + q1.z * wr2[6] + q1.w * wr2[7]
                    + q2.x * wr2[8] + q2.y * wr2[9] + q2.z * wr2[10] + q2.w * wr2[11];
      float e = __expf(x);
      float delta = (x > 15.f) ? x : __logf(1.f + e);
      float u = ureg[31 - tt];
      float du = delta * u;
      float rr = __builtin_amdgcn_rcpf(1.f + e);
      float pws[16]; pow16(rr, pws);
      const float4* Bq = (const float4*)(BsS + (lbr + tt) * 16);
      float4 b0 = Bq[0], b1 = Bq[1], b2 = Bq[2], b3 = Bq[3];
      float Bl[16] = {b0.x, b0.y, b0.z, b0.w, b1.x, b1.y, b1.z, b1.w,
                      b2.x, b2.y, b2.z, b2.w, b3.x, b3.y, b3.z, b3.w};
      const float4* Cq = (const float4*)(CsS + (lbr + tt) * 16);
      float4 c0 = Cq[0], c1 = Cq[1], c2 = Cq[2], c3 = Cq[3];
      float Cl[16] = {c0.x, c0.y, c0.z, c0.w, c1.x, c1.y, c1.z, c1.w,
                      c2.x, c2.y, c2.z, c2.w, c3.x, c3.y, c3.z, c3.w};
      float y = 0.f;
      #pragma unroll
      for (int n = 0; n < 16; n++) { h[n] = pws[n] * h[n] + du * Bl[n]; y += h[n] * Cl[n]; }
      yreg[31 - tt] += y;
    }
  } else {
    #pragma unroll
    for (int tt = 0; tt < 32; tt++) {
      const float4* dq = (const float4*)(dtsS + (lbr + tt) * 12);
      float4 q0 = dq[0], q1 = dq[1], q2 = dq[2];
      float x = dbr + q0.x * wr2[0] + q0.y * wr2[1] + q0.z * wr2[2] + q0.w * wr2[3]
                    + q1.x * wr2[4] + q1.y * wr2[5] + q1.z * wr2[6] + q1.w * wr2[7]
                    + q2.x * wr2[8] + q2.y * wr2[9] + q2.z * wr2[10] + q2.w * wr2[11];
      float e = __expf(x);
      float delta = (x > 15.f) ? x : __logf(1.f + e);
      float u = ureg[31 - tt];
      float du = delta * u;
      const float4* Bq = (const float4*)(BsS + (lbr + tt) * 16);
      float4 b0 = Bq[0], b1 = Bq[1], b2 = Bq[2], b3 = Bq[3];
      float Bl[16] = {b0.x, b0.y, b0.z, b0.w, b1.x, b1.y, b1.z, b1.w,
                      b2.x, b2.y, b2.z, b2.w, b3.x, b3.y, b3.z, b3.w};
      const float4* Cq = (const float4*)(CsS + (lbr + tt) * 16);
      float4 c0 = Cq[0], c1 = Cq[1], c2 = Cq[2], c3 = Cq[3];
      float Cl[16] = {c0.x, c0.y, c0.z, c0.w, c1.x, c1.y, c1.z, c1.w,
                      c2.x, c2.y, c2.z, c2.w, c3.x, c3.y, c3.z, c3.w};
      float y = 0.f;
      #pragma unroll
      for (int n = 0; n < 16; n++) {
        float dA = __expf(delta * avr[n]);
        h[n] = dA * h[n] + du * Bl[n];
        y += h[n] * Cl[n];
      }
      yreg[31 - tt] += y;
    }
  }
  // ---- single atomic per (pixel, d) for both chains ----
  #pragma unroll
  for (int t = 0; t < 32; t++) {
    int p = dir_pix(q, s * 32 + t);
    atomicAdd(&ysum[(bpix + p) * 384 + d], yreg[t]);
  }
}

// ---------------- merge: ysum + D-skip(bf16 xcb) + out-LN + silu(z bf16) -> bf16 ----------------
__global__ __launch_bounds__(384) void k_merge(const float* __restrict__ ysum,
                                               const __hip_bfloat16* __restrict__ xcb,
                                               const __hip_bfloat16* __restrict__ zbufB,
                                               const float* __restrict__ Ds,
                                               const float* __restrict__ g,
                                               const float* __restrict__ be,
                                               __hip_bfloat16* __restrict__ yactb) {
  int row = blockIdx.x;
  int d = threadIdx.x;
  float v = ysum[(long)row * 384 + d];
  float sd = Ds[d] + Ds[384 + d] + Ds[768 + d] + Ds[1152 + d];
  v += __bfloat162float(xcb[(long)row * 384 + d]) * sd;
  float s1 = v, s2 = v * v;
  #pragma unroll
  for (int o = 32; o > 0; o >>= 1) { s1 += __shfl_xor(s1, o); s2 += __shfl_xor(s2, o); }
  __shared__ float r1[6], r2[6];
  int wv = threadIdx.x >> 6;
  if ((threadIdx.x & 63) == 0) { r1[wv] = s1; r2[wv] = s2; }
  __syncthreads();
  float S1 = 0.f, S2 = 0.f;
  #pragma unroll
  for (int i = 0; i < 6; i++) { S1 += r1[i]; S2 += r2[i]; }
  float mu = S1 * (1.f / 384.f);
  float var = S2 * (1.f / 384.f) - mu * mu;
  float rr = rsqrtf(var + 1e-5f);
  float yn = (v - mu) * rr * g[d] + be[d];
  float z = __bfloat162float(zbufB[(long)row * 384 + d]);
  float sg = z / (1.f + __expf(-z));
  yactb[(long)row * 384 + d] = __float2bfloat16(yn * sg);
}

extern "C" void kernel_launch(void* const* d_in, const int* in_sizes, int n_in,
                              void* d_out, int out_size, void* d_ws, size_t ws_size,
                              hipStream_t stream) {
  const float* input      = (const float*)d_in[0];
  const float* norm_g     = (const float*)d_in[1];
  const float* norm_b     = (const float*)d_in[2];
  const float* in_proj_w  = (const float*)d_in[3];
  const float* conv_w     = (const float*)d_in[4];
  const float* conv_b     = (const float*)d_in[5];
  const float* x_proj_w   = (const float*)d_in[6];
  const float* dt_w       = (const float*)d_in[7];
  const float* dt_b       = (const float*)d_in[8];
  const float* A_logs     = (const float*)d_in[9];
  const float* Ds         = (const float*)d_in[10];
  const float* out_norm_g = (const float*)d_in[11];
  const float* out_norm_b = (const float*)d_in[12];
  const float* out_proj_w = (const float*)d_in[13];
  float* out = (float*)d_out;

  float* ws = (float*)d_ws;
  long o = 0;
  __hip_bfloat16* xnb   = (__hip_bfloat16*)(ws + o); o += 786432;   // 8192x192 bf16
  __hip_bfloat16* xbufB = (__hip_bfloat16*)(ws + o); o += 1572864;  // 8192x384 bf16
  __hip_bfloat16* zbufB = (__hip_bfloat16*)(ws + o); o += 1572864;
  __hip_bfloat16* xcb   = (__hip_bfloat16*)(ws + o); o += 1572864;
  __hip_bfloat16* Wt1   = (__hip_bfloat16*)(ws + o); o += 73728;    // 768x192 bf16
  __hip_bfloat16* Wt2   = (__hip_bfloat16*)(ws + o); o += 36864;    // 192x384 bf16
  __hip_bfloat16* Wt3   = (__hip_bfloat16*)(ws + o); o += 36864;
  float* dtsS           = ws + o;                    o += 393216;   // (BK,L,12)
  float* BsS            = ws + o;                    o += 524288;   // (BK,L,16)
  float* CsS            = ws + o;                    o += 524288;
  float* Eb             = ws + o;                    o += 6291456;  // (1024 segs, 6144)
  float* Dend           = ws + o;                    o += 393216;   // (1024, 384)
  float* Hb             = ws + o;                    o += 6291456;  // h_in per segment
  float* ysum           = ws + o;                    o += 3145728;  // (B,L,384) fp32
  __hip_bfloat16* yactb = (__hip_bfloat16*)(ws + o); o += 1572864;
  // total ≈ 24.5M floats ≈ 98 MB

  k_ln_packw<<<dim3(3200), dim3(256), 0, stream>>>(input, norm_g, norm_b,
                                                   in_proj_w, x_proj_w, out_proj_w,
                                                   xnb, Wt1, Wt2, Wt3);
  // in_proj: (8192x192)@(192x768), split bf16 epilogue -> xbufB/zbufB
  k_gemm_mfma<2><<<dim3(12, 128), dim3(256), 0, stream>>>(xnb, Wt1, nullptr, nullptr, xbufB, zbufB,
                                                          nullptr, nullptr, nullptr, 8192, 768, 192);
  k_conv<<<dim3(8192), dim3(384), 0, stream>>>(xbufB, conv_w, conv_b, xcb);
  // x_proj: (8192x384)@(384x192), scatter epilogue -> dtsS/BsS/CsS (scan order)
  k_gemm_mfma<3><<<dim3(3, 128), dim3(256), 0, stream>>>(xcb, Wt2, nullptr, nullptr, nullptr, nullptr,
                                                         dtsS, BsS, CsS, 8192, 192, 384);
  k_scan0<<<dim3(2048), dim3(192), 0, stream>>>(dtsS, BsS, xcb, A_logs, dt_w, dt_b, Eb, Dend, ysum);
  k_combine<<<dim3(768), dim3(64), 0, stream>>>(Eb, Dend, A_logs, Hb);
  k_scan1<<<dim3(1024), dim3(192), 0, stream>>>(dtsS, BsS, CsS, xcb, A_logs, dt_w, dt_b, Hb, ysum);
  k_merge<<<dim3(8192), dim3(384), 0, stream>>>(ysum, xcb, zbufB, Ds, out_norm_g, out_norm_b, yactb);
  // out_proj + residual: (8192x384)@(384x192) + input
  k_gemm_mfma<1><<<dim3(3, 128), dim3(256), 0, stream>>>(yactb, Wt3, input, out, nullptr, nullptr,
                                                         nullptr, nullptr, nullptr, 8192, 192, 384);
}

// Round 10
// 284.716 us; speedup vs baseline: 1.2613x; 1.2613x over previous
//
#include <hip/hip_runtime.h>
#include <hip/hip_bf16.h>

// VSSBlock: B=2 H=64 W=64 C=192 DM=384 N=16 R=12 K=4 L=4096
// R10: REVERT R9's direction-pairing (halved parallelism + VGPR 116 => 122us scan1).
//      Scans back to R8 shape: 1024 blocks x 384 threads each. Kept from R9:
//      ln+packw fused, ysum zeroing inside scan0, combine -> separate Hb.
//      New: h-update/y-dot written as float2 pairs to coax v_pk_fma_f32 (packed fp32).

typedef __attribute__((ext_vector_type(8))) short short8;     // 8 bf16 = 4 VGPRs
typedef __attribute__((ext_vector_type(4))) float floatx4;    // fp32 accum frag

__device__ __forceinline__ float2 pk_fma(float2 a, float2 b, float2 c) {
  return make_float2(fmaf(a.x, b.x, c.x), fmaf(a.y, b.y, c.y));
}
__device__ __forceinline__ float2 pk_mul(float2 a, float2 b) {
  return make_float2(a.x * b.x, a.y * b.y);
}

// ---------------- fused: LayerNorm (rows) + weight pack (tail blocks) ----------------
__global__ __launch_bounds__(256) void k_ln_packw(const float* __restrict__ in,
                                                  const float* __restrict__ g,
                                                  const float* __restrict__ be,
                                                  const float* __restrict__ ipw,
                                                  const float* __restrict__ xpw,
                                                  const float* __restrict__ opw,
                                                  __hip_bfloat16* __restrict__ xnb,
                                                  __hip_bfloat16* __restrict__ Wt1,
                                                  __hip_bfloat16* __restrict__ Wt2,
                                                  __hip_bfloat16* __restrict__ Wt3) {
  int bid = blockIdx.x;
  if (bid < 2048) {
    int row = bid * 4 + (threadIdx.x >> 6);
    int lane = threadIdx.x & 63;
    const float* x = in + (long)row * 192;
    float v0 = x[lane], v1 = x[lane + 64], v2 = x[lane + 128];
    float s = v0 + v1 + v2;
    float s2 = v0 * v0 + v1 * v1 + v2 * v2;
    #pragma unroll
    for (int o = 32; o > 0; o >>= 1) { s += __shfl_xor(s, o); s2 += __shfl_xor(s2, o); }
    float mu = s * (1.f / 192.f);
    float var = s2 * (1.f / 192.f) - mu * mu;
    float r = rsqrtf(var + 1e-6f);
    __hip_bfloat16* op = xnb + (long)row * 192;
    op[lane]       = __float2bfloat16((v0 - mu) * r * g[lane]       + be[lane]);
    op[lane + 64]  = __float2bfloat16((v1 - mu) * r * g[lane + 64]  + be[lane + 64]);
    op[lane + 128] = __float2bfloat16((v2 - mu) * r * g[lane + 128] + be[lane + 128]);
  } else {
    int idx = (bid - 2048) * 256 + threadIdx.x;
    if (idx < 147456) {                       // Wt1[n][k] = ipw[k][n]
      int n = idx / 192, k = idx - n * 192;
      Wt1[idx] = __float2bfloat16(ipw[(long)k * 768 + n]);
    } else if (idx < 147456 + 73728) {        // Wt2[j][d]
      int t = idx - 147456;
      int j = t / 384;
      float v = (j < 176) ? xpw[t] : 0.f;
      Wt2[t] = __float2bfloat16(v);
    } else if (idx < 147456 + 73728 + 73728) {// Wt3[n][k] = opw[k][n]
      int t = idx - 147456 - 73728;
      int n = t / 384, k = t - n * 384;
      Wt3[t] = __float2bfloat16(opw[(long)k * 192 + n]);
    }
  }
}

// direction map (involutions): pixel p <-> scan position l
__device__ __forceinline__ int inv_dir(int k, int p) {
  int pt = ((p & 63) << 6) | (p >> 6);
  if (k == 0) return p;
  if (k == 1) return pt;
  if (k == 2) return 4095 - p;
  return 4095 - pt;
}
__device__ __forceinline__ int dir_pix(int k, int l) { return inv_dir(k, l); }

// ---------------- bf16 MFMA GEMM: 64x64 tile, BK=64, XOR-swizzled LDS ----------------
// EPI 1: fp32 + Res; EPI 2: split bf16 -> CoB/Co2B [N=768]; EPI 3: scatter scan-order.
template <int EPI>
__global__ __launch_bounds__(256) void k_gemm_mfma(const __hip_bfloat16* __restrict__ A,
                                                   const __hip_bfloat16* __restrict__ Bt,
                                                   const float* __restrict__ Res,
                                                   float* __restrict__ Co,
                                                   __hip_bfloat16* __restrict__ CoB,
                                                   __hip_bfloat16* __restrict__ Co2B,
                                                   float* __restrict__ dtsS,
                                                   float* __restrict__ BsS,
                                                   float* __restrict__ CsS,
                                                   int M, int N, int Kk) {
  __shared__ __align__(16) short As[64 * 64];
  __shared__ __align__(16) short Bs[64 * 64];
  int tid = threadIdx.x;
  int wave = tid >> 6, lane = tid & 63;
  int mlane = lane & 15, quad = lane >> 4;
  int row0 = blockIdx.y * 64, col0 = blockIdx.x * 64;
  int wr = wave & 1, wc = wave >> 1;
  floatx4 acc[2][2];
  #pragma unroll
  for (int mi = 0; mi < 2; mi++)
    #pragma unroll
    for (int ni = 0; ni < 2; ni++) acc[mi][ni] = (floatx4){0.f, 0.f, 0.f, 0.f};

  for (int k0 = 0; k0 < Kk; k0 += 64) {
    #pragma unroll
    for (int c = tid; c < 512; c += 256) {
      int r = c >> 3, j = c & 7;
      *(float4*)&As[r * 64 + ((j ^ (r & 7)) << 3)] =
          *(const float4*)&A[(long)(row0 + r) * Kk + k0 + j * 8];
    }
    #pragma unroll
    for (int c = tid; c < 512; c += 256) {
      int r = c >> 3, j = c & 7;
      *(float4*)&Bs[r * 64 + ((j ^ (r & 7)) << 3)] =
          *(const float4*)&Bt[(long)(col0 + r) * Kk + k0 + j * 8];
    }
    __syncthreads();
    short8 af[2][2], bf[2][2];
    #pragma unroll
    for (int mi = 0; mi < 2; mi++) {
      int r = wr * 32 + mi * 16 + mlane;
      #pragma unroll
      for (int kk = 0; kk < 2; kk++) {
        int jx = (kk * 4 + quad) ^ (r & 7);
        af[mi][kk] = *(const short8*)&As[r * 64 + jx * 8];
      }
    }
    #pragma unroll
    for (int ni = 0; ni < 2; ni++) {
      int rn = wc * 32 + ni * 16 + mlane;
      #pragma unroll
      for (int kk = 0; kk < 2; kk++) {
        int jx = (kk * 4 + quad) ^ (rn & 7);
        bf[ni][kk] = *(const short8*)&Bs[rn * 64 + jx * 8];
      }
    }
    #pragma unroll
    for (int kk = 0; kk < 2; kk++)
      #pragma unroll
      for (int mi = 0; mi < 2; mi++)
        #pragma unroll
        for (int ni = 0; ni < 2; ni++)
          acc[mi][ni] = __builtin_amdgcn_mfma_f32_16x16x32_bf16(af[mi][kk], bf[ni][kk],
                                                                acc[mi][ni], 0, 0, 0);
    __syncthreads();
  }
  // C/D layout: col=lane&15, row=quad*4+reg  [m89-verified]
  #pragma unroll
  for (int mi = 0; mi < 2; mi++) {
    #pragma unroll
    for (int ni = 0; ni < 2; ni++) {
      int cc = col0 + wc * 32 + ni * 16 + mlane;
      #pragma unroll
      for (int i = 0; i < 4; i++) {
        int rr = row0 + wr * 32 + mi * 16 + quad * 4 + i;
        float v = acc[mi][ni][i];
        if (EPI == 1) {
          Co[(long)rr * N + cc] = v + Res[(long)rr * N + cc];
        } else if (EPI == 2) {
          if (cc < 384) CoB[(long)rr * 384 + cc] = __float2bfloat16(v);
          else          Co2B[(long)rr * 384 + (cc - 384)] = __float2bfloat16(v);
        } else {  // EPI == 3
          if (cc < 176) {
            int k4 = (cc >= 132) ? 3 : (cc >= 88) ? 2 : (cc >= 44) ? 1 : 0;
            int c = cc - k4 * 44;
            int b = rr >> 12, p = rr & 4095;
            int l = inv_dir(k4, p);
            long lbase = ((long)((b << 2) + k4) << 12) + l;
            if (c < 12)      dtsS[lbase * 12 + c] = v;
            else if (c < 28) BsS[lbase * 16 + (c - 12)] = v;
            else             CsS[lbase * 16 + (c - 28)] = v;
          }
        }
      }
    }
  }
}

// ---------------- depthwise 3x3 conv + bias + SiLU; bf16 in, bf16 out ----------------
__global__ __launch_bounds__(384) void k_conv(const __hip_bfloat16* __restrict__ xbufB,
                                              const float* __restrict__ cw,
                                              const float* __restrict__ cb,
                                              __hip_bfloat16* __restrict__ xcb) {
  int row = blockIdx.x;
  int b = row >> 12, p = row & 4095;
  int h = p >> 6, w0 = p & 63;
  int d = threadIdx.x;
  float acc = cb[d];
  const float* wt = cw + d * 9;
  #pragma unroll
  for (int dh = -1; dh <= 1; dh++) {
    int hh = h + dh;
    if (hh < 0 || hh > 63) continue;
    #pragma unroll
    for (int dw = -1; dw <= 1; dw++) {
      int ww = w0 + dw;
      if (ww < 0 || ww > 63) continue;
      acc += __bfloat162float(xbufB[((long)(b << 12) + (hh << 6) + ww) * 384 + d])
             * wt[(dh + 1) * 3 + (dw + 1)];
    }
  }
  float sg = 1.f / (1.f + __expf(-acc));
  xcb[(long)row * 384 + d] = __float2bfloat16(acc * sg);
}

// powers: pws[n] = r^(n+1), log-depth pairing
__device__ __forceinline__ void pow16(float r, float* pws) {
  pws[0] = r;
  #pragma unroll
  for (int n = 1; n < 16; n++) {
    int m = n + 1, c = (m + 1) / 2, f = m - c;
    pws[n] = pws[c - 1] * pws[f - 1];
  }
}

// ---------------- scan pass 0: 128 segs x 32 steps, 384 threads; also zeroes ysum ----
__global__ __launch_bounds__(384) void k_scan0(
    const float* __restrict__ dtsS, const float* __restrict__ BsS,
    const __hip_bfloat16* __restrict__ xcb,
    const float* __restrict__ A_logs, const float* __restrict__ dt_w,
    const float* __restrict__ dt_b,
    float* __restrict__ Eb, float* __restrict__ Dend,
    float* __restrict__ ysum) {
  int bid = blockIdx.x;
  {  // zero ysum slice: 1024 blocks x 3072 floats = 3,145,728
    float4 z4 = {0.f, 0.f, 0.f, 0.f};
    float4* zp = (float4*)(ysum + (long)bid * 3072) + threadIdx.x;
    zp[0] = z4; zp[384] = z4;
  }
  int s = bid & 127, bk = bid >> 7;
  int k = bk & 3, b = bk >> 2;
  int d = threadIdx.x;
  float w[12];
  const float* dwp = dt_w + ((long)(k * 384) + d) * 12;
  #pragma unroll
  for (int r = 0; r < 12; r++) w[r] = dwp[r];
  float db = dt_b[k * 384 + d];
  const float* al = A_logs + ((long)(k * 384) + d) * 16;
  bool pw = true;
  float av[16];
  #pragma unroll
  for (int n = 0; n < 16; n++) {
    float a = __expf(al[n]);
    av[n] = -a;
    pw = pw && (fabsf(a - (float)(n + 1)) < 1e-3f);
  }
  float cum = 0.f;
  long lb = (long)bk * 4096 + s * 32;
  long bpix = (long)(b << 12);

  if (pw) {
    float2 h2[8];
    #pragma unroll
    for (int i = 0; i < 8; i++) h2[i] = make_float2(0.f, 0.f);
    #pragma unroll 4
    for (int t = 0; t < 32; t++) {
      const float4* dq = (const float4*)(dtsS + (lb + t) * 12);
      float4 q0 = dq[0], q1 = dq[1], q2 = dq[2];
      float x = db + q0.x * w[0] + q0.y * w[1] + q0.z * w[2] + q0.w * w[3]
                   + q1.x * w[4] + q1.y * w[5] + q1.z * w[6] + q1.w * w[7]
                   + q2.x * w[8] + q2.y * w[9] + q2.z * w[10] + q2.w * w[11];
      float e = __expf(x);
      float delta = (x > 15.f) ? x : __logf(1.f + e);
      cum += delta;
      int p = dir_pix(k, s * 32 + t);
      float u = __bfloat162float(xcb[(bpix + p) * 384 + d]);
      float du = delta * u;
      float2 du2 = make_float2(du, du);
      float rr = __builtin_amdgcn_rcpf(1.f + e);  // exp(-softplus(x))
      float pws[16]; pow16(rr, pws);
      const float4* Bq = (const float4*)(BsS + (lb + t) * 16);
      float4 b0 = Bq[0], b1 = Bq[1], b2 = Bq[2], b3 = Bq[3];
      float2 B2[8] = {{b0.x, b0.y}, {b0.z, b0.w}, {b1.x, b1.y}, {b1.z, b1.w},
                      {b2.x, b2.y}, {b2.z, b2.w}, {b3.x, b3.y}, {b3.z, b3.w}};
      #pragma unroll
      for (int i = 0; i < 8; i++) {
        float2 p2 = make_float2(pws[2 * i], pws[2 * i + 1]);
        h2[i] = pk_fma(du2, B2[i], pk_mul(p2, h2[i]));
      }
    }
    long g = (long)bk * 128 + s;
    float* Ep = Eb + g * 6144 + d * 16;
    #pragma unroll
    for (int i = 0; i < 8; i++) { Ep[2 * i] = h2[i].x; Ep[2 * i + 1] = h2[i].y; }
    Dend[g * 384 + d] = cum;
  } else {
    float h[16];
    #pragma unroll
    for (int n = 0; n < 16; n++) h[n] = 0.f;
    for (int t = 0; t < 32; t++) {
      const float4* dq = (const float4*)(dtsS + (lb + t) * 12);
      float4 q0 = dq[0], q1 = dq[1], q2 = dq[2];
      float x = db + q0.x * w[0] + q0.y * w[1] + q0.z * w[2] + q0.w * w[3]
                   + q1.x * w[4] + q1.y * w[5] + q1.z * w[6] + q1.w * w[7]
                   + q2.x * w[8] + q2.y * w[9] + q2.z * w[10] + q2.w * w[11];
      float e = __expf(x);
      float delta = (x > 15.f) ? x : __logf(1.f + e);
      cum += delta;
      int p = dir_pix(k, s * 32 + t);
      float u = __bfloat162float(xcb[(bpix + p) * 384 + d]);
      float du = delta * u;
      const float4* Bq = (const float4*)(BsS + (lb + t) * 16);
      float4 b0 = Bq[0], b1 = Bq[1], b2 = Bq[2], b3 = Bq[3];
      float Bl[16] = {b0.x, b0.y, b0.z, b0.w, b1.x, b1.y, b1.z, b1.w,
                      b2.x, b2.y, b2.z, b2.w, b3.x, b3.y, b3.z, b3.w};
      #pragma unroll
      for (int n = 0; n < 16; n++) {
        float dA = __expf(delta * av[n]);
        h[n] = dA * h[n] + du * Bl[n];
      }
    }
    long g = (long)bk * 128 + s;
    float* Ep = Eb + g * 6144 + d * 16;
    #pragma unroll
    for (int n = 0; n < 16; n++) Ep[n] = h[n];
    Dend[g * 384 + d] = cum;
  }
}

// ---------------- combine: serial over 128 segs, h_in -> separate Hb ----------------
__global__ __launch_bounds__(64) void k_combine(const float* __restrict__ Eb,
                                                const float* __restrict__ Dend,
                                                const float* __restrict__ A_logs,
                                                float* __restrict__ Hb) {
  int t = blockIdx.x * 64 + threadIdx.x;  // B*K*6144 = 49152
  int bk = t / 6144;
  int dn = t - bk * 6144;
  int k = bk & 3;
  int d = dn >> 4;
  float av = -__expf(A_logs[(long)k * 6144 + dn]);
  float h = 0.f;
  long ebase = (long)bk * 128 * 6144 + dn;
  long dbase = (long)bk * 128 * 384 + d;
  for (int s = 0; s < 128; s++) {
    Hb[ebase + (long)s * 6144] = h;
    h = __expf(av * Dend[dbase + (long)s * 384]) * h + Eb[ebase + (long)s * 6144];
  }
}

// ---------------- scan pass 1: full recurrence from Hb, atomicAdd y into ysum ----------------
__global__ __launch_bounds__(384) void k_scan1(
    const float* __restrict__ dtsS, const float* __restrict__ BsS,
    const float* __restrict__ CsS, const __hip_bfloat16* __restrict__ xcb,
    const float* __restrict__ A_logs, const float* __restrict__ dt_w,
    const float* __restrict__ dt_b, const float* __restrict__ Hb,
    float* __restrict__ ysum) {
  int bid = blockIdx.x;
  int s = bid & 127, bk = bid >> 7;
  int k = bk & 3, b = bk >> 2;
  int d = threadIdx.x;
  float w[12];
  const float* dwp = dt_w + ((long)(k * 384) + d) * 12;
  #pragma unroll
  for (int r = 0; r < 12; r++) w[r] = dwp[r];
  float db = dt_b[k * 384 + d];
  const float* al = A_logs + ((long)(k * 384) + d) * 16;
  bool pw = true;
  float av[16];
  #pragma unroll
  for (int n = 0; n < 16; n++) {
    float a = __expf(al[n]);
    av[n] = -a;
    pw = pw && (fabsf(a - (float)(n + 1)) < 1e-3f);
  }
  long lb = (long)bk * 4096 + s * 32;
  long bpix = (long)(b << 12);
  const float* hp = Hb + ((long)bk * 128 + s) * 6144 + d * 16;

  if (pw) {
    float2 h2[8];
    #pragma unroll
    for (int i = 0; i < 8; i++) h2[i] = make_float2(hp[2 * i], hp[2 * i + 1]);
    #pragma unroll 4
    for (int t = 0; t < 32; t++) {
      const float4* dq = (const float4*)(dtsS + (lb + t) * 12);
      float4 q0 = dq[0], q1 = dq[1], q2 = dq[2];
      float x = db + q0.x * w[0] + q0.y * w[1] + q0.z * w[2] + q0.w * w[3]
                   + q1.x * w[4] + q1.y * w[5] + q1.z * w[6] + q1.w * w[7]
                   + q2.x * w[8] + q2.y * w[9] + q2.z * w[10] + q2.w * w[11];
      float e = __expf(x);
      float delta = (x > 15.f) ? x : __logf(1.f + e);
      int p = dir_pix(k, s * 32 + t);
      float u = __bfloat162float(xcb[(bpix + p) * 384 + d]);
      float du = delta * u;
      float2 du2 = make_float2(du, du);
      float rr = __builtin_amdgcn_rcpf(1.f + e);
      float pws[16]; pow16(rr, pws);
      const float4* Bq = (const float4*)(BsS + (lb + t) * 16);
      float4 b0 = Bq[0], b1 = Bq[1], b2 = Bq[2], b3 = Bq[3];
      float2 B2[8] = {{b0.x, b0.y}, {b0.z, b0.w}, {b1.x, b1.y}, {b1.z, b1.w},
                      {b2.x, b2.y}, {b2.z, b2.w}, {b3.x, b3.y}, {b3.z, b3.w}};
      const float4* Cq = (const float4*)(CsS + (lb + t) * 16);
      float4 c0 = Cq[0], c1 = Cq[1], c2 = Cq[2], c3 = Cq[3];
      float2 C2[8] = {{c0.x, c0.y}, {c0.z, c0.w}, {c1.x, c1.y}, {c1.z, c1.w},
                      {c2.x, c2.y}, {c2.z, c2.w}, {c3.x, c3.y}, {c3.z, c3.w}};
      float2 y2 = make_float2(0.f, 0.f);
      #pragma unroll
      for (int i = 0; i < 8; i++) {
        float2 p2 = make_float2(pws[2 * i], pws[2 * i + 1]);
        h2[i] = pk_fma(du2, B2[i], pk_mul(p2, h2[i]));
        y2 = pk_fma(h2[i], C2[i], y2);
      }
      atomicAdd(&ysum[(bpix + p) * 384 + d], y2.x + y2.y);
    }
  } else {
    float h[16];
    #pragma unroll
    for (int n = 0; n < 16; n++) h[n] = hp[n];
    for (int t = 0; t < 32; t++) {
      const float4* dq = (const float4*)(dtsS + (lb + t) * 12);
      float4 q0 = dq[0], q1 = dq[1], q2 = dq[2];
      float x = db + q0.x * w[0] + q0.y * w[1] + q0.z * w[2] + q0.w * w[3]
                   + q1.x * w[4] + q1.y * w[5] + q1.z * w[6] + q1.w * w[7]
                   + q2.x * w[8] + q2.y * w[9] + q2.z * w[10] + q2.w * w[11];
      float e = __expf(x);
      float delta = (x > 15.f) ? x : __logf(1.f + e);
      int p = dir_pix(k, s * 32 + t);
      float u = __bfloat162float(xcb[(bpix + p) * 384 + d]);
      float du = delta * u;
      const float4* Bq = (const float4*)(BsS + (lb + t) * 16);
      float4 b0 = Bq[0], b1 = Bq[1], b2 = Bq[2], b3 = Bq[3];
      float Bl[16] = {b0.x, b0.y, b0.z, b0.w, b1.x, b1.y, b1.z, b1.w,
                      b2.x, b2.y, b2.z, b2.w, b3.x, b3.y, b3.z, b3.w};
      const float4* Cq = (const float4*)(CsS + (lb + t) * 16);
      float4 c0 = Cq[0], c1 = Cq[1], c2 = Cq[2], c3 = Cq[3];
      float Cl[16] = {c0.x, c0.y, c0.z, c0.w, c1.x, c1.y, c1.z, c1.w,
                      c2.x, c2.y, c2.z, c2.w, c3.x, c3.y, c3.z, c3.w};
      float y = 0.f;
      #pragma unroll
      for (int n = 0; n < 16; n++) {
        float dA = __expf(delta * av[n]);
        h[n] = dA * h[n] + du * Bl[n];
        y += h[n] * Cl[n];
      }
      atomicAdd(&ysum[(bpix + p) * 384 + d], y);
    }
  }
}

// ---------------- merge: ysum + D-skip(bf16 xcb) + out-LN + silu(z bf16) -> bf16 ----------------
__global__ __launch_bounds__(384) void k_merge(const float* __restrict__ ysum,
                                               const __hip_bfloat16* __restrict__ xcb,
                                               const __hip_bfloat16* __restrict__ zbufB,
                                               const float* __restrict__ Ds,
                                               const float* __restrict__ g,
                                               const float* __restrict__ be,
                                               __hip_bfloat16* __restrict__ yactb) {
  int row = blockIdx.x;
  int d = threadIdx.x;
  float v = ysum[(long)row * 384 + d];
  float sd = Ds[d] + Ds[384 + d] + Ds[768 + d] + Ds[1152 + d];
  v += __bfloat162float(xcb[(long)row * 384 + d]) * sd;
  float s1 = v, s2 = v * v;
  #pragma unroll
  for (int o = 32; o > 0; o >>= 1) { s1 += __shfl_xor(s1, o); s2 += __shfl_xor(s2, o); }
  __shared__ float r1[6], r2[6];
  int wv = threadIdx.x >> 6;
  if ((threadIdx.x & 63) == 0) { r1[wv] = s1; r2[wv] = s2; }
  __syncthreads();
  float S1 = 0.f, S2 = 0.f;
  #pragma unroll
  for (int i = 0; i < 6; i++) { S1 += r1[i]; S2 += r2[i]; }
  float mu = S1 * (1.f / 384.f);
  float var = S2 * (1.f / 384.f) - mu * mu;
  float rr = rsqrtf(var + 1e-5f);
  float yn = (v - mu) * rr * g[d] + be[d];
  float z = __bfloat162float(zbufB[(long)row * 384 + d]);
  float sg = z / (1.f + __expf(-z));
  yactb[(long)row * 384 + d] = __float2bfloat16(yn * sg);
}

extern "C" void kernel_launch(void* const* d_in, const int* in_sizes, int n_in,
                              void* d_out, int out_size, void* d_ws, size_t ws_size,
                              hipStream_t stream) {
  const float* input      = (const float*)d_in[0];
  const float* norm_g     = (const float*)d_in[1];
  const float* norm_b     = (const float*)d_in[2];
  const float* in_proj_w  = (const float*)d_in[3];
  const float* conv_w     = (const float*)d_in[4];
  const float* conv_b     = (const float*)d_in[5];
  const float* x_proj_w   = (const float*)d_in[6];
  const float* dt_w       = (const float*)d_in[7];
  const float* dt_b       = (const float*)d_in[8];
  const float* A_logs     = (const float*)d_in[9];
  const float* Ds         = (const float*)d_in[10];
  const float* out_norm_g = (const float*)d_in[11];
  const float* out_norm_b = (const float*)d_in[12];
  const float* out_proj_w = (const float*)d_in[13];
  float* out = (float*)d_out;

  float* ws = (float*)d_ws;
  long o = 0;
  __hip_bfloat16* xnb   = (__hip_bfloat16*)(ws + o); o += 786432;   // 8192x192 bf16
  __hip_bfloat16* xbufB = (__hip_bfloat16*)(ws + o); o += 1572864;  // 8192x384 bf16
  __hip_bfloat16* zbufB = (__hip_bfloat16*)(ws + o); o += 1572864;
  __hip_bfloat16* xcb   = (__hip_bfloat16*)(ws + o); o += 1572864;
  __hip_bfloat16* Wt1   = (__hip_bfloat16*)(ws + o); o += 73728;    // 768x192 bf16
  __hip_bfloat16* Wt2   = (__hip_bfloat16*)(ws + o); o += 36864;    // 192x384 bf16
  __hip_bfloat16* Wt3   = (__hip_bfloat16*)(ws + o); o += 36864;
  float* dtsS           = ws + o;                    o += 393216;   // (BK,L,12)
  float* BsS            = ws + o;                    o += 524288;   // (BK,L,16)
  float* CsS            = ws + o;                    o += 524288;
  float* Eb             = ws + o;                    o += 6291456;  // (1024 segs, 6144)
  float* Dend           = ws + o;                    o += 393216;   // (1024, 384)
  float* Hb             = ws + o;                    o += 6291456;  // h_in per segment
  float* ysum           = ws + o;                    o += 3145728;  // (B,L,384) fp32
  __hip_bfloat16* yactb = (__hip_bfloat16*)(ws + o); o += 1572864;
  // total ≈ 24.5M floats ≈ 98 MB

  k_ln_packw<<<dim3(3200), dim3(256), 0, stream>>>(input, norm_g, norm_b,
                                                   in_proj_w, x_proj_w, out_proj_w,
                                                   xnb, Wt1, Wt2, Wt3);
  // in_proj: (8192x192)@(192x768), split bf16 epilogue -> xbufB/zbufB
  k_gemm_mfma<2><<<dim3(12, 128), dim3(256), 0, stream>>>(xnb, Wt1, nullptr, nullptr, xbufB, zbufB,
                                                          nullptr, nullptr, nullptr, 8192, 768, 192);
  k_conv<<<dim3(8192), dim3(384), 0, stream>>>(xbufB, conv_w, conv_b, xcb);
  // x_proj: (8192x384)@(384x192), scatter epilogue -> dtsS/BsS/CsS (scan order)
  k_gemm_mfma<3><<<dim3(3, 128), dim3(256), 0, stream>>>(xcb, Wt2, nullptr, nullptr, nullptr, nullptr,
                                                         dtsS, BsS, CsS, 8192, 192, 384);
  k_scan0<<<dim3(1024), dim3(384), 0, stream>>>(dtsS, BsS, xcb, A_logs, dt_w, dt_b, Eb, Dend, ysum);
  k_combine<<<dim3(768), dim3(64), 0, stream>>>(Eb, Dend, A_logs, Hb);
  k_scan1<<<dim3(1024), dim3(384), 0, stream>>>(dtsS, BsS, CsS, xcb, A_logs, dt_w, dt_b, Hb, ysum);
  k_merge<<<dim3(8192), dim3(384), 0, stream>>>(ysum, xcb, zbufB, Ds, out_norm_g, out_norm_b, yactb);
  // out_proj + residual: (8192x384)@(384x192) + input
  k_gemm_mfma<1><<<dim3(3, 128), dim3(256), 0, stream>>>(yactb, Wt3, input, out, nullptr, nullptr,
                                                         nullptr, nullptr, nullptr, 8192, 192, 384);
}